// Round 22
// baseline (70.523 us; speedup 1.0000x reference)
//
#include <hip/hip_runtime.h>
#include <math.h>

typedef _Float16 f16;
typedef __attribute__((ext_vector_type(4))) _Float16 f16x4;
typedef __attribute__((ext_vector_type(8))) _Float16 f16x8;
typedef __attribute__((ext_vector_type(4))) float f32x4;

#define Bn 4
#define Ln 256
#define Qn 128
#define Hn 1024
#define LBL 33
#define POUT 32896   // 256*257/2

__device__ __forceinline__ float gelu_exact(float x){
    return 0.5f * x * (1.0f + erff(x * 0.70710678118654752f));
}

__device__ __forceinline__ bool mask_at(const void* m, int idx, unsigned u0){
    if (u0 == 0x01010101u) return ((const unsigned char*)m)[idx] != 0;
    if (u0 == 0x3f800000u) return ((const float*)m)[idx] != 0.0f;
    return ((const int*)m)[idx] != 0;
}

__device__ __forceinline__ void gload16(const void* g, void* l){
    __builtin_amdgcn_global_load_lds(
        (const __attribute__((address_space(1))) unsigned int*)g,
        (__attribute__((address_space(3))) unsigned int*)l, 16, 0, 0);
}

// ---------------- prep: weight cvt/transpose only (input cvt eliminated) ----------------
__global__ __launch_bounds__(256) void prep(
    const float* __restrict__ cls_w1, const float* __restrict__ loc_w1,
    const float* __restrict__ tq_w,  const float* __restrict__ tc_w,
    f16* __restrict__ Wq_t, f16* __restrict__ Wc_t)
{
    const int tile = blockIdx.x, t = threadIdx.x;   // 0..2559
    const float* src; f16* dst; int id, lg;
    if      (tile < 256)  { id = tile;        src = cls_w1; dst = Wq_t;                     lg = 4; }
    else if (tile < 512)  { id = tile - 256;  src = loc_w1; dst = Wq_t + (size_t)512*1024;  lg = 4; }
    else if (tile < 1536) { id = tile - 512;  src = tq_w;   dst = Wq_t + (size_t)1024*1024; lg = 6; }
    else                  { id = tile - 1536; src = tc_w;   dst = Wc_t;                     lg = 6; }
    const int N  = 32 << lg;
    const int n0 = (id & ((1<<lg)-1)) * 32;
    const int k0 = (id >> lg) * 64;

    __shared__ float X[64][33];
    const int rr = t >> 3, c4 = (t & 7) * 4;
    const float4 v0 = *(const float4*)&src[(size_t)(k0 + rr)      * N + n0 + c4];
    const float4 v1 = *(const float4*)&src[(size_t)(k0 + rr + 32) * N + n0 + c4];
    X[rr   ][c4+0] = v0.x; X[rr   ][c4+1] = v0.y; X[rr   ][c4+2] = v0.z; X[rr   ][c4+3] = v0.w;
    X[rr+32][c4+0] = v1.x; X[rr+32][c4+1] = v1.y; X[rr+32][c4+2] = v1.z; X[rr+32][c4+3] = v1.w;
    __syncthreads();
    const int n = t >> 3, kc = (t & 7) * 8;
    f16x8 o;
    #pragma unroll
    for (int u = 0; u < 8; u++) o[u] = (f16)X[kc + u][n];
    *(f16x8*)&dst[(size_t)(n0 + n) * 1024 + k0 + kc] = o;
}

// ---------------- GEMM: 128M x 64N tiles, 448 blocks, 2D-chunked XCD swizzle, K=1024 ----------------
// A-operand read DIRECTLY as f32 (reg-staged, cvt->f16, swizzled ds_write matching the
// gload16 layout: LDS slot s of row r holds global k-chunk s^(r&7)). W via gload16 (f16).
__global__ __launch_bounds__(256) void gemm128(
    const float* __restrict__ Aq, const float* __restrict__ Ac,
    const f16* __restrict__ Wq, const f16* __restrict__ Wc,
    const float* __restrict__ cb1, const float* __restrict__ lb1,
    const float* __restrict__ tqb, const float* __restrict__ tcb,
    float* __restrict__ X1, float* __restrict__ X2,
    f16* __restrict__ qh, f16* __restrict__ chh)
{
    __shared__ __align__(16) f16 Ah[128*64];
    __shared__ __align__(16) f16 Bh[64*64];
    const int tid = threadIdx.x;
    const int w = tid >> 6, lane = tid & 63;
    const int wr = w >> 1, wcc = w & 1;
    const int lr = lane & 15, hi = lane >> 4;

    const int bid = blockIdx.x;
    const int k   = bid & 7;        // XCD chunk
    const int o   = bid >> 3;       // ordinal within chunk, 0..55
    const float* A; const f16* Bt;
    int bm, bn, qside;
    if (o < 24) {                   // q-side: chunk = 2bm x 12bn
        qside = 1; A = Aq; Bt = Wq;
        bm = (k >> 2) * 2 + o / 12;
        bn = (k & 3) * 12 + o % 12;
    } else {                        // c-side: chunk = 4bm x 8bn
        qside = 0; A = Ac; Bt = Wc;
        const int oc = o - 24;
        bm = (k & 1) * 4 + oc / 8;
        bn = (k >> 1) * 8 + oc % 8;
    }

    const int lr8   = lane >> 3;
    const int lslot = (lane & 7) ^ lr8;
    const float* Ag = A  + (size_t)(bm*128 + w*32) * 1024;
    const f16*   Bg = Bt + (size_t)(bn*64 + w*16) * 1024;
    f16* AhW = &Ah[(w*32)*64];
    f16* BhW = &Bh[(w*16)*64];

    f32x4 acc[4][2] = {};

    for (int k0 = 0; k0 < 1024; k0 += 64) {
        // A: f32 reg-stage -> f16 swizzled LDS (same layout gload16 would produce)
        #pragma unroll
        for (int i = 0; i < 4; i++) {
            const float* ap = Ag + (size_t)(i*8 + lr8)*1024 + k0 + lslot*8;
            const float4 a0 = *(const float4*)(ap);
            const float4 a1 = *(const float4*)(ap + 4);
            f16x8 av;
            av[0]=(f16)a0.x; av[1]=(f16)a0.y; av[2]=(f16)a0.z; av[3]=(f16)a0.w;
            av[4]=(f16)a1.x; av[5]=(f16)a1.y; av[6]=(f16)a1.z; av[7]=(f16)a1.w;
            *(f16x8*)&AhW[i*512 + lane*8] = av;
        }
        // B: async f16 gload16 (pre-transposed)
        #pragma unroll
        for (int i = 0; i < 2; i++)
            gload16(Bg + (size_t)(i*8 + lr8)*1024 + k0 + lslot*8, BhW + i*8*64);
        __syncthreads();
        #pragma unroll
        for (int ks = 0; ks < 2; ks++) {
            f16x8 a[4], b[2];
            #pragma unroll
            for (int mf = 0; mf < 4; mf++) {
                const int row = wr*64 + mf*16 + lr;
                const int sl  = (ks*4 + hi) ^ (lr & 7);
                a[mf] = *(const f16x8*)&Ah[row*64 + sl*8];
            }
            #pragma unroll
            for (int nf = 0; nf < 2; nf++) {
                const int row = wcc*32 + nf*16 + lr;
                const int sl  = (ks*4 + hi) ^ (lr & 7);
                b[nf] = *(const f16x8*)&Bh[row*64 + sl*8];
            }
            #pragma unroll
            for (int mf = 0; mf < 4; mf++)
                #pragma unroll
                for (int nf = 0; nf < 2; nf++)
                    acc[mf][nf] = __builtin_amdgcn_mfma_f32_16x16x32_f16(a[mf], b[nf], acc[mf][nf], 0, 0, 0);
        }
        __syncthreads();
    }

    const int r0 = hi * 4;
    #pragma unroll
    for (int nf = 0; nf < 2; nf++) {
        const int colg = bn*64 + wcc*32 + nf*16 + lr;
        if (qside) {
            if (bn < 8) {
                const float bv = cb1[colg];
                #pragma unroll
                for (int mf = 0; mf < 4; mf++)
                    #pragma unroll
                    for (int r = 0; r < 4; r++) {
                        const int row = bm*128 + wr*64 + mf*16 + r0 + r;
                        X1[(size_t)row*512 + colg] = gelu_exact(acc[mf][nf][r] + bv);
                    }
            } else if (bn < 16) {
                const int c2 = colg - 512;
                const float bv = lb1[c2];
                #pragma unroll
                for (int mf = 0; mf < 4; mf++)
                    #pragma unroll
                    for (int r = 0; r < 4; r++) {
                        const int row = bm*128 + wr*64 + mf*16 + r0 + r;
                        X2[(size_t)row*512 + c2] = gelu_exact(acc[mf][nf][r] + bv);
                    }
            } else {
                const int c2 = colg - 1024;
                const float bv = tqb[c2];
                #pragma unroll
                for (int mf = 0; mf < 4; mf++)
                    #pragma unroll
                    for (int r = 0; r < 4; r++) {
                        const int row = bm*128 + wr*64 + mf*16 + r0 + r;
                        qh[(size_t)row*2048 + c2] = (f16)(acc[mf][nf][r] + bv);
                    }
            }
        } else {
            const float bv = tcb[colg];
            #pragma unroll
            for (int mf = 0; mf < 4; mf++)
                #pragma unroll
                for (int r = 0; r < 4; r++) {
                    const int row = bm*128 + wr*64 + mf*16 + r0 + r;
                    chh[(size_t)row*2048 + colg] = (f16)(acc[mf][nf][r] + bv);
                }
        }
    }
}

// ---------------- fused: blocks [0,128) score einsum 32x64 tiles ; [128,640) cls ; [640,1152) loc ----------------
__global__ __launch_bounds__(256) void score_heads(
    const f16* __restrict__ qh, const f16* __restrict__ chh,
    const void* __restrict__ maskp, float* __restrict__ score,
    const float* __restrict__ X1, const float* __restrict__ cls_w2,
    const float* __restrict__ cls_b2, const float* __restrict__ qlog, float* __restrict__ out0,
    const float* __restrict__ X2, const float* __restrict__ loc_w2,
    const float* __restrict__ loc_b2, const float* __restrict__ qlocs, float* __restrict__ geo)
{
    __shared__ __align__(16) char smem[64*72*2*2 + 64];
    const int bx = blockIdx.x, tid = threadIdx.x;

    if (bx < 128) {
        // ----- score path: 32x64 tile -----
        f16* Ah = (f16*)smem;             // [32][72]
        f16* Bh = Ah + 32*72;             // [64][72]
        const int bc = bx & 7, b = bc >> 1, c = bc & 1;
        const int n0 = ((bx >> 3) & 3) * 64;
        const int m0 = (bx >> 5) * 32;
        const f16* Aq = qh  + (size_t)b*Qn*2048 + c*1024;
        const f16* Bv = chh + (size_t)b*Ln*2048 + c*1024;

        const int w = tid >> 6, lane = tid & 63;
        const int wr = w >> 1, wc = w & 1;
        const int lr = lane & 15, lk = (lane >> 4) * 8;
        const int rr = tid >> 3, gg = (tid & 7) * 8;

        f32x4 acc[2] = {};

        for (int k0 = 0; k0 < 1024; k0 += 64) {
            *(f16x8*)&Ah[(rr   )*72 + gg] = *(const f16x8*)(Aq + (size_t)(m0+rr   )*2048 + k0 + gg);
            *(f16x8*)&Bh[(rr   )*72 + gg] = *(const f16x8*)(Bv + (size_t)(n0+rr   )*2048 + k0 + gg);
            *(f16x8*)&Bh[(rr+32)*72 + gg] = *(const f16x8*)(Bv + (size_t)(n0+rr+32)*2048 + k0 + gg);
            __syncthreads();
            #pragma unroll
            for (int ks=0; ks<64; ks+=32){
                f16x8 a, b2[2];
                a = *(f16x8*)&Ah[(wr*16+lr)*72 + ks+lk];
                #pragma unroll
                for (int nf=0; nf<2; nf++) b2[nf] = *(f16x8*)&Bh[(wc*32+nf*16+lr)*72 + ks+lk];
                #pragma unroll
                for (int nf=0; nf<2; nf++)
                    acc[nf] = __builtin_amdgcn_mfma_f32_16x16x32_f16(a, b2[nf], acc[nf], 0, 0, 0);
            }
            __syncthreads();
        }

        const unsigned u0 = *(const unsigned*)maskp;
        const int r0 = (lane >> 4) * 4;
        #pragma unroll
        for (int nf=0; nf<2; nf++){
            const int v = n0 + wc*32 + nf*16 + lr;
            const bool mv = mask_at(maskp, b*Ln + v, u0);
            #pragma unroll
            for (int r=0; r<4; r++){
                const int q = m0 + wr*16 + r0 + r;
                float val = mv ? (acc[nf][r] * 0.03125f) : -100000000.0f;
                score[((size_t)(b*2+c)*Qn + q)*Ln + v] = val;
            }
        }
    } else if (bx < 640) {
        // ----- cls softmax path -----
        float* xr = (float*)smem;         // 512
        float* lg = xr + 512;             // 64
        float* sc = lg + 64;              // 2
        const int row = bx - 128, t = tid;
        xr[t]       = X1[(size_t)row*512 + t];
        xr[t + 256] = X1[(size_t)row*512 + t + 256];
        __syncthreads();
        const int c = t >> 2, s = t & 3;
        float acc = 0.0f;
        if (c < LBL){
            for (int k = s*128; k < (s+1)*128; k++) acc += xr[k] * cls_w2[(size_t)k*LBL + c];
        }
        acc += __shfl_down(acc, 1);
        acc += __shfl_down(acc, 2);
        if (s == 0 && c < LBL) lg[c] = acc + cls_b2[c] + qlog[(size_t)row*LBL + c];
        __syncthreads();
        if (t == 0){
            float mx = -1e30f;
            for (int k=0;k<LBL;k++) mx = fmaxf(mx, lg[k]);
            float sm = 0.0f;
            for (int k=0;k<LBL;k++) sm += __expf(lg[k]-mx);
            sc[0] = mx; sc[1] = 1.0f / sm;
        }
        __syncthreads();
        if (t < LBL) out0[(size_t)row*LBL + t] = __expf(lg[t]-sc[0]) * sc[1];
    } else {
        // ----- loc geo path -----
        float* xr = (float*)smem;
        float* lg = xr + 512;
        const int row = bx - 640, t = tid;
        xr[t]       = X2[(size_t)row*512 + t];
        xr[t + 256] = X2[(size_t)row*512 + t + 256];
        __syncthreads();
        const int c = t >> 5, s = t & 31;
        float acc = 0.0f;
        if (c < 6){
            for (int k = s*16; k < (s+1)*16; k++) acc += xr[k] * loc_w2[(size_t)k*6 + c];
        }
        #pragma unroll
        for (int off=1; off<32; off<<=1) acc += __shfl_down(acc, off);
        if (s == 0 && c < 6) lg[c] = acc + loc_b2[c];
        __syncthreads();
        if (t == 0){
            const float o0=lg[0], o1=lg[1], f0=lg[2], f1=lg[3], f2=lg[4], f3=lg[5];
            geo[(size_t)row*5+0] = qlocs[(size_t)row*2+0] + o0;
            geo[(size_t)row*5+1] = qlocs[(size_t)row*2+1] + o1;
            geo[(size_t)row*5+2] = f0*f0 + f1*f1;
            geo[(size_t)row*5+3] = f0*f2 + f1*f3;
            geo[(size_t)row*5+4] = f2*f2 + f3*f3;
        }
    }
}

// ---------------- pair softmax v8: flat float4 single-pass + padded T (proven) ----------------
__global__ __launch_bounds__(1024, 8) void pair_fused(
    const float* __restrict__ score, const float* __restrict__ geo,
    float* __restrict__ out1)
{
    const int bq = blockIdx.x, b = bq >> 7, t = threadIdx.x;
    __shared__ float s0[256], s1[256];
    __shared__ float2 RG[256];
    __shared__ float T[288];
    __shared__ float red[16];
    __shared__ float bcv;

    const float* sc0 = score + ((size_t)(b*2)*Qn + (bq & 127))*Ln;
    if (t < 256)      s0[t]       = sc0[t];
    else if (t < 512) s1[t - 256] = sc0[(size_t)Qn*Ln + (t - 256)];
    __syncthreads();

    const int lane = t & 63;
    const float4 s1v = *(const float4*)&s1[lane*4];
    const float4 s0v = *(const float4*)&s0[lane*4];
    float sfx = fmaxf(fmaxf(s1v.x, s1v.y), fmaxf(s1v.z, s1v.w));
    #pragma unroll
    for (int off = 1; off < 64; off <<= 1) {
        const int src = (lane + off < 64) ? (lane + off) : 63;
        const float v = __shfl(sfx, src, 64);
        if (lane + off < 64) sfx = fmaxf(sfx, v);
    }
    float nxt = __shfl(sfx, (lane < 63) ? (lane + 1) : 63, 64);
    if (lane == 63) nxt = -3.0e38f;
    float run = fmaxf(nxt, s1v.w);
    float cand = s0v.w + run;
    run = fmaxf(run, s1v.z); cand = fmaxf(cand, s0v.z + run);
    run = fmaxf(run, s1v.y); cand = fmaxf(cand, s0v.y + run);
    run = fmaxf(run, s1v.x); cand = fmaxf(cand, s0v.x + run);
    #pragma unroll
    for (int off = 1; off < 64; off <<= 1) cand = fmaxf(cand, __shfl_xor(cand, off, 64));
    const float m = cand;

    const float c0  = geo[(size_t)bq*5+0], c1  = geo[(size_t)bq*5+1];
    const float F00 = geo[(size_t)bq*5+2], F01 = geo[(size_t)bq*5+3], F11 = geo[(size_t)bq*5+4];

    if (t < 256) {
        const float d0 = (float)t - c0;
        const float nG = -2.0f * F01 * d0;
        const float Rv = s0[t] - F00 * d0 * d0 - m;
        RG[t] = make_float2(Rv - nG * c1, nG);
        const float d1 = (float)t - c1;
        T[t + (t >> 3)] = s1[t] - F11 * d1 * d1;
    }
    __syncthreads();

    float ev[32];
    float lsum = 0.0f;
    #pragma unroll
    for (int kk = 0; kk < 8; kk++) {
        const int p = kk*4096 + 4*t;
        const float sq = sqrtf((float)(263169 - 8*p));
        int i = (int)((513.0f - sq) * 0.5f);
        int j = i + (p - ((i*(513 - i)) >> 1));
        #pragma unroll
        for (int u = 0; u < 4; u++) {
            const float2 rg = RG[i];
            const float e = __expf(fmaf(rg.y, (float)j, rg.x) + T[j + (j >> 3)]);
            ev[kk*4 + u] = e;
            lsum += e;
            j++;
            const bool wrap = (j > 255);
            i += wrap ? 1 : 0;
            j = wrap ? i : j;
        }
    }
    if (t < 32) {
        const int p = 32768 + 4*t;
        const float sq = sqrtf((float)(263169 - 8*p));
        int i = (int)((513.0f - sq) * 0.5f);
        int j = i + (p - ((i*(513 - i)) >> 1));
        #pragma unroll
        for (int u = 0; u < 4; u++) {
            const float2 rg = RG[i];
            lsum += __expf(fmaf(rg.y, (float)j, rg.x) + T[j + (j >> 3)]);
            j++;
            const bool wrap = (j > 255);
            i += wrap ? 1 : 0;
            j = wrap ? i : j;
        }
    }

    #pragma unroll
    for (int off = 1; off < 64; off <<= 1) lsum += __shfl_xor(lsum, off, 64);
    if (lane == 0) red[t >> 6] = lsum;
    __syncthreads();
    if (t == 0) {
        float tot = 0.0f;
        #pragma unroll
        for (int k = 0; k < 16; k++) tot += red[k];
        bcv = 1.0f / (tot + 1e-12f);
    }
    __syncthreads();
    const float inv = bcv;

    float* op = out1 + (size_t)bq * POUT;
    #pragma unroll
    for (int kk = 0; kk < 8; kk++) {
        const int p = kk*4096 + 4*t;
        f32x4 v;
        v[0] = ev[kk*4]*inv; v[1] = ev[kk*4+1]*inv; v[2] = ev[kk*4+2]*inv; v[3] = ev[kk*4+3]*inv;
        *(f32x4*)&op[p] = v;
    }
    if (t < 32) {
        const int p = 32768 + 4*t;
        const float sq = sqrtf((float)(263169 - 8*p));
        int i = (int)((513.0f - sq) * 0.5f);
        int j = i + (p - ((i*(513 - i)) >> 1));
        f32x4 v;
        #pragma unroll
        for (int u = 0; u < 4; u++) {
            const float2 rg = RG[i];
            v[u] = __expf(fmaf(rg.y, (float)j, rg.x) + T[j + (j >> 3)]) * inv;
            j++;
            const bool wrap = (j > 255);
            i += wrap ? 1 : 0;
            j = wrap ? i : j;
        }
        *(f32x4*)&op[p] = v;
    }
}

extern "C" void kernel_launch(void* const* d_in, const int* in_sizes, int n_in,
                              void* d_out, int out_size, void* d_ws, size_t ws_size,
                              hipStream_t stream)
{
    const float* hiddens = (const float*)d_in[0];
    const void*  masks   = d_in[1];
    const float* queries = (const float*)d_in[2];
    const float* qlocs   = (const float*)d_in[3];
    const float* qlogits = (const float*)d_in[4];
    const float* cls_w1  = (const float*)d_in[5];
    const float* cls_b1  = (const float*)d_in[6];
    const float* cls_w2  = (const float*)d_in[7];
    const float* cls_b2  = (const float*)d_in[8];
    const float* tq_w    = (const float*)d_in[9];
    const float* tq_b    = (const float*)d_in[10];
    const float* tc_w    = (const float*)d_in[11];
    const float* tc_b    = (const float*)d_in[12];
    const float* loc_w1  = (const float*)d_in[13];
    const float* loc_b1  = (const float*)d_in[14];
    const float* loc_w2  = (const float*)d_in[15];
    const float* loc_b2  = (const float*)d_in[16];

    char* ws = (char*)d_ws;
    float* X1    = (float*)(ws + (3u<<20));          // 1 MB  (512x512)
    float* X2    = (float*)(ws + (4u<<20));          // 1 MB
    f16*   qh    = (f16*)  (ws + (5u<<20));          // 2 MB  (512x2048)
    float* score = (float*)(ws + (7u<<20));          // 1 MB  (B,2,Q,L)
    float* geo   = (float*)(ws + (8u<<20));          // 10 KB

    float* out0 = (float*)d_out;
    float* out1 = out0 + (size_t)Bn*Qn*LBL;

    // big transient scratch inside out1 (fully overwritten by pair_fused at the end)
    f16* Wq_t = (f16*)out1;                                   // 3072x1024 f16 = 6 MB
    f16* Wc_t = (f16*)((char*)out1 + 6291456);                // 2048x1024 f16 = 4 MB
    f16* chh  = (f16*)((char*)out1 + 6291456 + 4194304);      // 1024x2048 f16 = 4 MB

    prep<<<dim3(2560), 256, 0, stream>>>(cls_w1, loc_w1, tq_w, tc_w, Wq_t, Wc_t);
    gemm128<<<dim3(448), 256, 0, stream>>>(queries, hiddens, Wq_t, Wc_t,
                                           cls_b1, loc_b1, tq_b, tc_b,
                                           X1, X2, qh, chh);
    score_heads<<<dim3(1152), 256, 0, stream>>>(qh, chh, masks, score,
                                                X1, cls_w2, cls_b2, qlogits, out0,
                                                X2, loc_w2, loc_b2, qlocs, geo);
    pair_fused<<<dim3(Bn*Qn), 1024, 0, stream>>>(score, geo, out1);
}

// Round 23
// 64.645 us; speedup vs baseline: 1.0909x; 1.0909x over previous
//
#include <hip/hip_runtime.h>
#include <math.h>

typedef _Float16 f16;
typedef __attribute__((ext_vector_type(4))) _Float16 f16x4;
typedef __attribute__((ext_vector_type(8))) _Float16 f16x8;
typedef __attribute__((ext_vector_type(4))) float f32x4;

#define Bn 4
#define Ln 256
#define Qn 128
#define Hn 1024
#define LBL 33
#define POUT 32896   // 256*257/2

__device__ __forceinline__ float gelu_exact(float x){
    return 0.5f * x * (1.0f + erff(x * 0.70710678118654752f));
}

__device__ __forceinline__ bool mask_at(const void* m, int idx, unsigned u0){
    if (u0 == 0x01010101u) return ((const unsigned char*)m)[idx] != 0;
    if (u0 == 0x3f800000u) return ((const float*)m)[idx] != 0.0f;
    return ((const int*)m)[idx] != 0;
}

__device__ __forceinline__ void gload16(const void* g, void* l){
    __builtin_amdgcn_global_load_lds(
        (const __attribute__((address_space(1))) unsigned int*)g,
        (__attribute__((address_space(3))) unsigned int*)l, 16, 0, 0);
}

// ---------------- prep: input f32->f16 cvt + weight cvt/transpose ----------------
__global__ __launch_bounds__(256) void prep(
    const float* __restrict__ q, const float* __restrict__ h,
    const float* __restrict__ cls_w1, const float* __restrict__ loc_w1,
    const float* __restrict__ tq_w,  const float* __restrict__ tc_w,
    f16* __restrict__ qf, f16* __restrict__ hf,
    f16* __restrict__ Wq_t, f16* __restrict__ Wc_t)
{
    const int bx = blockIdx.x, t = threadIdx.x;
    if (bx < 1536) {
        if (bx < 512) {
            const int gid = bx*256 + t;
            const float4 v = ((const float4*)q)[gid];
            f16x4 o; o[0]=(f16)v.x; o[1]=(f16)v.y; o[2]=(f16)v.z; o[3]=(f16)v.w;
            *(f16x4*)&qf[(size_t)gid*4] = o;
        } else {
            const int gid = (bx-512)*256 + t;
            const float4 v = ((const float4*)h)[gid];
            f16x4 o; o[0]=(f16)v.x; o[1]=(f16)v.y; o[2]=(f16)v.z; o[3]=(f16)v.w;
            *(f16x4*)&hf[(size_t)gid*4] = o;
        }
        return;
    }
    const int tile = bx - 1536;     // 0..2559
    const float* src; f16* dst; int id, lg;
    if      (tile < 256)  { id = tile;        src = cls_w1; dst = Wq_t;                     lg = 4; }
    else if (tile < 512)  { id = tile - 256;  src = loc_w1; dst = Wq_t + (size_t)512*1024;  lg = 4; }
    else if (tile < 1536) { id = tile - 512;  src = tq_w;   dst = Wq_t + (size_t)1024*1024; lg = 6; }
    else                  { id = tile - 1536; src = tc_w;   dst = Wc_t;                     lg = 6; }
    const int N  = 32 << lg;
    const int n0 = (id & ((1<<lg)-1)) * 32;
    const int k0 = (id >> lg) * 64;

    __shared__ float X[64][33];
    const int rr = t >> 3, c4 = (t & 7) * 4;
    const float4 v0 = *(const float4*)&src[(size_t)(k0 + rr)      * N + n0 + c4];
    const float4 v1 = *(const float4*)&src[(size_t)(k0 + rr + 32) * N + n0 + c4];
    X[rr   ][c4+0] = v0.x; X[rr   ][c4+1] = v0.y; X[rr   ][c4+2] = v0.z; X[rr   ][c4+3] = v0.w;
    X[rr+32][c4+0] = v1.x; X[rr+32][c4+1] = v1.y; X[rr+32][c4+2] = v1.z; X[rr+32][c4+3] = v1.w;
    __syncthreads();
    const int n = t >> 3, kc = (t & 7) * 8;
    f16x8 o;
    #pragma unroll
    for (int u = 0; u < 8; u++) o[u] = (f16)X[kc + u][n];
    *(f16x8*)&dst[(size_t)(n0 + n) * 1024 + k0 + kc] = o;
}

// ---------------- GEMM: 128M x 64N tiles, 448 blocks (~1.75/CU TLP), K=1024 ----------------
__global__ __launch_bounds__(256) void gemm128(
    const f16* __restrict__ Aq, const f16* __restrict__ Ac,
    const f16* __restrict__ Wq, const f16* __restrict__ Wc,
    const float* __restrict__ cb1, const float* __restrict__ lb1,
    const float* __restrict__ tqb, const float* __restrict__ tcb,
    float* __restrict__ X1, float* __restrict__ X2,
    f16* __restrict__ qh, f16* __restrict__ chh)
{
    __shared__ __align__(16) f16 Ah[128*64];
    __shared__ __align__(16) f16 Bh[64*64];
    const int tid = threadIdx.x;
    const int w = tid >> 6, lane = tid & 63;
    const int wr = w >> 1, wcc = w & 1;
    const int lr = lane & 15, hi = lane >> 4;

    const int bx = blockIdx.x;
    const f16 *A, *Bt;
    int bm, bn, qside;
    if (bx < 192) { qside = 1; bm = bx / 48; bn = bx % 48; A = Aq; Bt = Wq; }
    else          { qside = 0; const int ix = bx - 192; bm = ix >> 5; bn = ix & 31; A = Ac; Bt = Wc; }

    const int lr8   = lane >> 3;
    const int lslot = (lane & 7) ^ lr8;
    const f16* Ag = A  + (size_t)(bm*128 + w*32) * 1024;
    const f16* Bg = Bt + (size_t)(bn*64 + w*16) * 1024;
    f16* AhW = &Ah[(w*32)*64];
    f16* BhW = &Bh[(w*16)*64];

    f32x4 acc[4][2] = {};

    for (int k0 = 0; k0 < 1024; k0 += 64) {
        #pragma unroll
        for (int i = 0; i < 4; i++)
            gload16(Ag + (size_t)(i*8 + lr8)*1024 + k0 + lslot*8, AhW + i*8*64);
        #pragma unroll
        for (int i = 0; i < 2; i++)
            gload16(Bg + (size_t)(i*8 + lr8)*1024 + k0 + lslot*8, BhW + i*8*64);
        __syncthreads();
        #pragma unroll
        for (int ks = 0; ks < 2; ks++) {
            f16x8 a[4], b[2];
            #pragma unroll
            for (int mf = 0; mf < 4; mf++) {
                const int row = wr*64 + mf*16 + lr;
                const int sl  = (ks*4 + hi) ^ (lr & 7);
                a[mf] = *(const f16x8*)&Ah[row*64 + sl*8];
            }
            #pragma unroll
            for (int nf = 0; nf < 2; nf++) {
                const int row = wcc*32 + nf*16 + lr;
                const int sl  = (ks*4 + hi) ^ (lr & 7);
                b[nf] = *(const f16x8*)&Bh[row*64 + sl*8];
            }
            #pragma unroll
            for (int mf = 0; mf < 4; mf++)
                #pragma unroll
                for (int nf = 0; nf < 2; nf++)
                    acc[mf][nf] = __builtin_amdgcn_mfma_f32_16x16x32_f16(a[mf], b[nf], acc[mf][nf], 0, 0, 0);
        }
        __syncthreads();
    }

    const int r0 = hi * 4;
    #pragma unroll
    for (int nf = 0; nf < 2; nf++) {
        const int colg = bn*64 + wcc*32 + nf*16 + lr;
        if (qside) {
            if (bn < 8) {
                const float bv = cb1[colg];
                #pragma unroll
                for (int mf = 0; mf < 4; mf++)
                    #pragma unroll
                    for (int r = 0; r < 4; r++) {
                        const int row = bm*128 + wr*64 + mf*16 + r0 + r;
                        X1[(size_t)row*512 + colg] = gelu_exact(acc[mf][nf][r] + bv);
                    }
            } else if (bn < 16) {
                const int c2 = colg - 512;
                const float bv = lb1[c2];
                #pragma unroll
                for (int mf = 0; mf < 4; mf++)
                    #pragma unroll
                    for (int r = 0; r < 4; r++) {
                        const int row = bm*128 + wr*64 + mf*16 + r0 + r;
                        X2[(size_t)row*512 + c2] = gelu_exact(acc[mf][nf][r] + bv);
                    }
            } else {
                const int c2 = colg - 1024;
                const float bv = tqb[c2];
                #pragma unroll
                for (int mf = 0; mf < 4; mf++)
                    #pragma unroll
                    for (int r = 0; r < 4; r++) {
                        const int row = bm*128 + wr*64 + mf*16 + r0 + r;
                        qh[(size_t)row*2048 + c2] = (f16)(acc[mf][nf][r] + bv);
                    }
            }
        } else {
            const float bv = tcb[colg];
            #pragma unroll
            for (int mf = 0; mf < 4; mf++)
                #pragma unroll
                for (int r = 0; r < 4; r++) {
                    const int row = bm*128 + wr*64 + mf*16 + r0 + r;
                    chh[(size_t)row*2048 + colg] = (f16)(acc[mf][nf][r] + bv);
                }
        }
    }
}

// ---------------- fused: blocks [0,128) score einsum 32x64 tiles ; [128,640) cls ; [640,1152) loc ----------------
__global__ __launch_bounds__(256) void score_heads(
    const f16* __restrict__ qh, const f16* __restrict__ chh,
    const void* __restrict__ maskp, float* __restrict__ score,
    const float* __restrict__ X1, const float* __restrict__ cls_w2,
    const float* __restrict__ cls_b2, const float* __restrict__ qlog, float* __restrict__ out0,
    const float* __restrict__ X2, const float* __restrict__ loc_w2,
    const float* __restrict__ loc_b2, const float* __restrict__ qlocs, float* __restrict__ geo)
{
    __shared__ __align__(16) char smem[64*72*2*2 + 64];
    const int bx = blockIdx.x, tid = threadIdx.x;

    if (bx < 128) {
        // ----- score path: 32x64 tile -----
        f16* Ah = (f16*)smem;             // [32][72]
        f16* Bh = Ah + 32*72;             // [64][72]
        const int bc = bx & 7, b = bc >> 1, c = bc & 1;
        const int n0 = ((bx >> 3) & 3) * 64;
        const int m0 = (bx >> 5) * 32;
        const f16* Aq = qh  + (size_t)b*Qn*2048 + c*1024;
        const f16* Bv = chh + (size_t)b*Ln*2048 + c*1024;

        const int w = tid >> 6, lane = tid & 63;
        const int wr = w >> 1, wc = w & 1;
        const int lr = lane & 15, lk = (lane >> 4) * 8;
        const int rr = tid >> 3, gg = (tid & 7) * 8;

        f32x4 acc[2] = {};

        for (int k0 = 0; k0 < 1024; k0 += 64) {
            *(f16x8*)&Ah[(rr   )*72 + gg] = *(const f16x8*)(Aq + (size_t)(m0+rr   )*2048 + k0 + gg);
            *(f16x8*)&Bh[(rr   )*72 + gg] = *(const f16x8*)(Bv + (size_t)(n0+rr   )*2048 + k0 + gg);
            *(f16x8*)&Bh[(rr+32)*72 + gg] = *(const f16x8*)(Bv + (size_t)(n0+rr+32)*2048 + k0 + gg);
            __syncthreads();
            #pragma unroll
            for (int ks=0; ks<64; ks+=32){
                f16x8 a, b2[2];
                a = *(f16x8*)&Ah[(wr*16+lr)*72 + ks+lk];
                #pragma unroll
                for (int nf=0; nf<2; nf++) b2[nf] = *(f16x8*)&Bh[(wc*32+nf*16+lr)*72 + ks+lk];
                #pragma unroll
                for (int nf=0; nf<2; nf++)
                    acc[nf] = __builtin_amdgcn_mfma_f32_16x16x32_f16(a, b2[nf], acc[nf], 0, 0, 0);
            }
            __syncthreads();
        }

        const unsigned u0 = *(const unsigned*)maskp;
        const int r0 = (lane >> 4) * 4;
        #pragma unroll
        for (int nf=0; nf<2; nf++){
            const int v = n0 + wc*32 + nf*16 + lr;
            const bool mv = mask_at(maskp, b*Ln + v, u0);
            #pragma unroll
            for (int r=0; r<4; r++){
                const int q = m0 + wr*16 + r0 + r;
                float val = mv ? (acc[nf][r] * 0.03125f) : -100000000.0f;
                score[((size_t)(b*2+c)*Qn + q)*Ln + v] = val;
            }
        }
    } else if (bx < 640) {
        // ----- cls softmax path -----
        float* xr = (float*)smem;         // 512
        float* lg = xr + 512;             // 64
        float* sc = lg + 64;              // 2
        const int row = bx - 128, t = tid;
        xr[t]       = X1[(size_t)row*512 + t];
        xr[t + 256] = X1[(size_t)row*512 + t + 256];
        __syncthreads();
        const int c = t >> 2, s = t & 3;
        float acc = 0.0f;
        if (c < LBL){
            for (int k = s*128; k < (s+1)*128; k++) acc += xr[k] * cls_w2[(size_t)k*LBL + c];
        }
        acc += __shfl_down(acc, 1);
        acc += __shfl_down(acc, 2);
        if (s == 0 && c < LBL) lg[c] = acc + cls_b2[c] + qlog[(size_t)row*LBL + c];
        __syncthreads();
        if (t == 0){
            float mx = -1e30f;
            for (int k=0;k<LBL;k++) mx = fmaxf(mx, lg[k]);
            float sm = 0.0f;
            for (int k=0;k<LBL;k++) sm += __expf(lg[k]-mx);
            sc[0] = mx; sc[1] = 1.0f / sm;
        }
        __syncthreads();
        if (t < LBL) out0[(size_t)row*LBL + t] = __expf(lg[t]-sc[0]) * sc[1];
    } else {
        // ----- loc geo path -----
        float* xr = (float*)smem;
        float* lg = xr + 512;
        const int row = bx - 640, t = tid;
        xr[t]       = X2[(size_t)row*512 + t];
        xr[t + 256] = X2[(size_t)row*512 + t + 256];
        __syncthreads();
        const int c = t >> 5, s = t & 31;
        float acc = 0.0f;
        if (c < 6){
            for (int k = s*16; k < (s+1)*16; k++) acc += xr[k] * loc_w2[(size_t)k*6 + c];
        }
        #pragma unroll
        for (int off=1; off<32; off<<=1) acc += __shfl_down(acc, off);
        if (s == 0 && c < 6) lg[c] = acc + loc_b2[c];
        __syncthreads();
        if (t == 0){
            const float o0=lg[0], o1=lg[1], f0=lg[2], f1=lg[3], f2=lg[4], f3=lg[5];
            geo[(size_t)row*5+0] = qlocs[(size_t)row*2+0] + o0;
            geo[(size_t)row*5+1] = qlocs[(size_t)row*2+1] + o1;
            geo[(size_t)row*5+2] = f0*f0 + f1*f1;
            geo[(size_t)row*5+3] = f0*f2 + f1*f3;
            geo[(size_t)row*5+4] = f2*f2 + f3*f3;
        }
    }
}

// ---------------- pair softmax v8: flat float4 single-pass + padded T (proven) ----------------
__global__ __launch_bounds__(1024, 8) void pair_fused(
    const float* __restrict__ score, const float* __restrict__ geo,
    float* __restrict__ out1)
{
    const int bq = blockIdx.x, b = bq >> 7, t = threadIdx.x;
    __shared__ float s0[256], s1[256];
    __shared__ float2 RG[256];
    __shared__ float T[288];
    __shared__ float red[16];
    __shared__ float bcv;

    const float* sc0 = score + ((size_t)(b*2)*Qn + (bq & 127))*Ln;
    if (t < 256)      s0[t]       = sc0[t];
    else if (t < 512) s1[t - 256] = sc0[(size_t)Qn*Ln + (t - 256)];
    __syncthreads();

    const int lane = t & 63;
    const float4 s1v = *(const float4*)&s1[lane*4];
    const float4 s0v = *(const float4*)&s0[lane*4];
    float sfx = fmaxf(fmaxf(s1v.x, s1v.y), fmaxf(s1v.z, s1v.w));
    #pragma unroll
    for (int off = 1; off < 64; off <<= 1) {
        const int src = (lane + off < 64) ? (lane + off) : 63;
        const float v = __shfl(sfx, src, 64);
        if (lane + off < 64) sfx = fmaxf(sfx, v);
    }
    float nxt = __shfl(sfx, (lane < 63) ? (lane + 1) : 63, 64);
    if (lane == 63) nxt = -3.0e38f;
    float run = fmaxf(nxt, s1v.w);
    float cand = s0v.w + run;
    run = fmaxf(run, s1v.z); cand = fmaxf(cand, s0v.z + run);
    run = fmaxf(run, s1v.y); cand = fmaxf(cand, s0v.y + run);
    run = fmaxf(run, s1v.x); cand = fmaxf(cand, s0v.x + run);
    #pragma unroll
    for (int off = 1; off < 64; off <<= 1) cand = fmaxf(cand, __shfl_xor(cand, off, 64));
    const float m = cand;

    const float c0  = geo[(size_t)bq*5+0], c1  = geo[(size_t)bq*5+1];
    const float F00 = geo[(size_t)bq*5+2], F01 = geo[(size_t)bq*5+3], F11 = geo[(size_t)bq*5+4];

    if (t < 256) {
        const float d0 = (float)t - c0;
        const float nG = -2.0f * F01 * d0;
        const float Rv = s0[t] - F00 * d0 * d0 - m;
        RG[t] = make_float2(Rv - nG * c1, nG);
        const float d1 = (float)t - c1;
        T[t + (t >> 3)] = s1[t] - F11 * d1 * d1;
    }
    __syncthreads();

    float ev[32];
    float lsum = 0.0f;
    #pragma unroll
    for (int kk = 0; kk < 8; kk++) {
        const int p = kk*4096 + 4*t;
        const float sq = sqrtf((float)(263169 - 8*p));
        int i = (int)((513.0f - sq) * 0.5f);
        int j = i + (p - ((i*(513 - i)) >> 1));
        #pragma unroll
        for (int u = 0; u < 4; u++) {
            const float2 rg = RG[i];
            const float e = __expf(fmaf(rg.y, (float)j, rg.x) + T[j + (j >> 3)]);
            ev[kk*4 + u] = e;
            lsum += e;
            j++;
            const bool wrap = (j > 255);
            i += wrap ? 1 : 0;
            j = wrap ? i : j;
        }
    }
    if (t < 32) {
        const int p = 32768 + 4*t;
        const float sq = sqrtf((float)(263169 - 8*p));
        int i = (int)((513.0f - sq) * 0.5f);
        int j = i + (p - ((i*(513 - i)) >> 1));
        #pragma unroll
        for (int u = 0; u < 4; u++) {
            const float2 rg = RG[i];
            lsum += __expf(fmaf(rg.y, (float)j, rg.x) + T[j + (j >> 3)]);
            j++;
            const bool wrap = (j > 255);
            i += wrap ? 1 : 0;
            j = wrap ? i : j;
        }
    }

    #pragma unroll
    for (int off = 1; off < 64; off <<= 1) lsum += __shfl_xor(lsum, off, 64);
    if (lane == 0) red[t >> 6] = lsum;
    __syncthreads();
    if (t == 0) {
        float tot = 0.0f;
        #pragma unroll
        for (int k = 0; k < 16; k++) tot += red[k];
        bcv = 1.0f / (tot + 1e-12f);
    }
    __syncthreads();
    const float inv = bcv;

    float* op = out1 + (size_t)bq * POUT;
    #pragma unroll
    for (int kk = 0; kk < 8; kk++) {
        const int p = kk*4096 + 4*t;
        f32x4 v;
        v[0] = ev[kk*4]*inv; v[1] = ev[kk*4+1]*inv; v[2] = ev[kk*4+2]*inv; v[3] = ev[kk*4+3]*inv;
        *(f32x4*)&op[p] = v;
    }
    if (t < 32) {
        const int p = 32768 + 4*t;
        const float sq = sqrtf((float)(263169 - 8*p));
        int i = (int)((513.0f - sq) * 0.5f);
        int j = i + (p - ((i*(513 - i)) >> 1));
        f32x4 v;
        #pragma unroll
        for (int u = 0; u < 4; u++) {
            const float2 rg = RG[i];
            v[u] = __expf(fmaf(rg.y, (float)j, rg.x) + T[j + (j >> 3)]) * inv;
            j++;
            const bool wrap = (j > 255);
            i += wrap ? 1 : 0;
            j = wrap ? i : j;
        }
        *(f32x4*)&op[p] = v;
    }
}

extern "C" void kernel_launch(void* const* d_in, const int* in_sizes, int n_in,
                              void* d_out, int out_size, void* d_ws, size_t ws_size,
                              hipStream_t stream)
{
    const float* hiddens = (const float*)d_in[0];
    const void*  masks   = d_in[1];
    const float* queries = (const float*)d_in[2];
    const float* qlocs   = (const float*)d_in[3];
    const float* qlogits = (const float*)d_in[4];
    const float* cls_w1  = (const float*)d_in[5];
    const float* cls_b1  = (const float*)d_in[6];
    const float* cls_w2  = (const float*)d_in[7];
    const float* cls_b2  = (const float*)d_in[8];
    const float* tq_w    = (const float*)d_in[9];
    const float* tq_b    = (const float*)d_in[10];
    const float* tc_w    = (const float*)d_in[11];
    const float* tc_b    = (const float*)d_in[12];
    const float* loc_w1  = (const float*)d_in[13];
    const float* loc_b1  = (const float*)d_in[14];
    const float* loc_w2  = (const float*)d_in[15];
    const float* loc_b2  = (const float*)d_in[16];

    char* ws = (char*)d_ws;
    f16*   qf16  = (f16*)  (ws);                     // 1 MB  (512x1024)
    f16*   hf16  = (f16*)  (ws + (1u<<20));          // 2 MB  (1024x1024)
    float* X1    = (float*)(ws + (3u<<20));          // 1 MB  (512x512)
    float* X2    = (float*)(ws + (4u<<20));          // 1 MB
    f16*   qh    = (f16*)  (ws + (5u<<20));          // 2 MB  (512x2048)
    float* score = (float*)(ws + (7u<<20));          // 1 MB  (B,2,Q,L)
    float* geo   = (float*)(ws + (8u<<20));          // 10 KB

    float* out0 = (float*)d_out;
    float* out1 = out0 + (size_t)Bn*Qn*LBL;

    // big transient scratch inside out1 (fully overwritten by pair_fused at the end)
    f16* Wq_t = (f16*)out1;                                   // 3072x1024 f16 = 6 MB
    f16* Wc_t = (f16*)((char*)out1 + 6291456);                // 2048x1024 f16 = 4 MB
    f16* chh  = (f16*)((char*)out1 + 6291456 + 4194304);      // 1024x2048 f16 = 4 MB

    prep<<<dim3(4096), 256, 0, stream>>>(queries, hiddens, cls_w1, loc_w1, tq_w, tc_w,
                                         qf16, hf16, Wq_t, Wc_t);
    gemm128<<<dim3(448), 256, 0, stream>>>(qf16, hf16, Wq_t, Wc_t,
                                           cls_b1, loc_b1, tq_b, tc_b,
                                           X1, X2, qh, chh);
    score_heads<<<dim3(1152), 256, 0, stream>>>(qh, chh, masks, score,
                                                X1, cls_w2, cls_b2, qlogits, out0,
                                                X2, loc_w2, loc_b2, qlocs, geo);
    pair_fused<<<dim3(Bn*Qn), 1024, 0, stream>>>(score, geo, out1);
}